// Round 3
// baseline (2112.801 us; speedup 1.0000x reference)
//
#include <hip/hip_runtime.h>
#include <stdint.h>

#define NA 100000
#define NE 200000
#define NLG 400000
#define NG 1024
#define AF 39
#define BFD 11
#define HID 300
#define DEPTH 6

#define E_PAD 200064    // edges padded to multiple of 128
#define A_PAD 100096    // atoms padded to multiple of 128
#define MS 304          // msg row stride in u16 (608 B -> 16B aligned)
#define NT 20           // N tiles (320 cols, 300 real)

typedef unsigned short u16;
typedef __attribute__((ext_vector_type(8))) short s8v;            // 8 bf16 bits (A/B frag)
typedef __attribute__((ext_vector_type(8))) unsigned short u16x8;
typedef __attribute__((ext_vector_type(4))) float f4v;            // C/D frag

__device__ inline u16 f2bf(float x){
  unsigned u = __float_as_uint(x);
  u += 0x7FFFu + ((u>>16)&1u);   // RNE
  return (u16)(u>>16);
}
__device__ inline float bf2f(u16 b){ return __uint_as_float(((unsigned)b)<<16); }

#define GLOAD_LDS16(gp, lp) __builtin_amdgcn_global_load_lds( \
    (const __attribute__((address_space(1))) void*)(gp), \
    (__attribute__((address_space(3))) void*)(lp), 16, 0, 0)

// ---------------- weight packing to fragment order ----------------
// B-frag element (kt, nt, lane, j) <-> B[k = kt*32 + (lane>>4)*8 + j][n = nt*16 + (lane&15)]
// stacked [W_i ; zero-pad ; W_h]: k<50 -> W_i[k]; 64<=k<364 -> W_h[k-64]; else 0
__global__ void prep_whi(const float* __restrict__ Wi, const float* __restrict__ Wh,
                         u16* __restrict__ Wf){
  int idx = blockIdx.x*256 + threadIdx.x;
  const int total = 12*NT*512;
  if (idx >= total) return;
  int j    = idx & 7;
  int lane = (idx>>3) & 63;
  int tile = idx >> 9;
  int nt = tile % NT, kt = tile / NT;
  int k = kt*32 + ((lane>>4)<<3) + j;
  int n = nt*16 + (lane&15);
  float v = 0.f;
  if (n < HID){
    if (k < AF+BFD) v = Wi[(size_t)k*HID + n];
    else if (k >= 64 && k < 64+HID) v = Wh[(size_t)(k-64)*HID + n];
  }
  Wf[idx] = f2bf(v);
}

// W_o row remap: k<39 -> k ; 48<=k<348 -> k-9 ; else zero   (W_o has 339 rows)
__global__ void prep_wo(const float* __restrict__ W, u16* __restrict__ Wf){
  int idx = blockIdx.x*256 + threadIdx.x;
  const int total = 11*NT*512;
  if (idx >= total) return;
  int j    = idx & 7;
  int lane = (idx>>3) & 63;
  int tile = idx >> 9;
  int nt = tile % NT, kt = tile / NT;
  int k = kt*32 + ((lane>>4)<<3) + j;
  int n = nt*16 + (lane&15);
  int ks = (k < AF) ? k : ((k >= 48 && k < 348) ? (k-9) : -1);
  float v = 0.f;
  if (ks >= 0 && n < HID) v = W[(size_t)ks*HID + n];
  Wf[idx] = f2bf(v);
}

// ---------------- CSR build ----------------
__global__ void hist_k(const int* __restrict__ dst, int* __restrict__ cnt, int n){
  int i = blockIdx.x*256 + threadIdx.x;
  if (i < n) atomicAdd(&cnt[dst[i]], 1);
}
__global__ void scan1(const int* __restrict__ cnt, int* __restrict__ off,
                      int* __restrict__ part, int n){
  __shared__ int s[256];
  const int t = threadIdx.x, b = blockIdx.x;
  const int i0 = b*1024 + t*4;
  int v0 = (i0+0<n)?cnt[i0+0]:0, v1=(i0+1<n)?cnt[i0+1]:0, v2=(i0+2<n)?cnt[i0+2]:0, v3=(i0+3<n)?cnt[i0+3]:0;
  int sum = v0+v1+v2+v3;
  s[t]=sum; __syncthreads();
  for (int o=1;o<256;o<<=1){ int x=(t>=o)?s[t-o]:0; __syncthreads(); s[t]+=x; __syncthreads(); }
  int excl = s[t]-sum;
  if (i0+0<n) off[i0+0]=excl;
  if (i0+1<n) off[i0+1]=excl+v0;
  if (i0+2<n) off[i0+2]=excl+v0+v1;
  if (i0+3<n) off[i0+3]=excl+v0+v1+v2;
  if (t==255) part[b]=s[255];
}
__global__ void scan2(const int* __restrict__ part, int* __restrict__ pref, int nblk){
  __shared__ int s[256];
  const int t = threadIdx.x;
  int v = (t<nblk)?part[t]:0;
  s[t]=v; __syncthreads();
  for (int o=1;o<256;o<<=1){ int x=(t>=o)?s[t-o]:0; __syncthreads(); s[t]+=x; __syncthreads(); }
  pref[t] = s[t]-v;
}
__global__ void scan3(int* __restrict__ off, const int* __restrict__ pref,
                      const int* __restrict__ part, int n, int nblk){
  const int t = threadIdx.x, b = blockIdx.x;
  const int i0 = b*1024 + t*4;
  const int p = pref[b];
  #pragma unroll
  for (int k=0;k<4;++k) if (i0+k<n) off[i0+k]+=p;
  if (b==0 && t==0) off[n] = pref[nblk-1] + part[nblk-1];
}
__global__ void scatter_val(const int* __restrict__ dst, const int* __restrict__ src,
                            const int* __restrict__ off, int* __restrict__ cur,
                            int* __restrict__ csr, int n){
  int i = blockIdx.x*256 + threadIdx.x; if (i>=n) return;
  int d = dst[i];
  int p = off[d] + atomicAdd(&cur[d],1);
  csr[p] = src[i];
}
__global__ void scatter_idx(const int* __restrict__ dst, const int* __restrict__ off,
                            int* __restrict__ cur, int* __restrict__ csr, int n){
  int i = blockIdx.x*256 + threadIdx.x; if (i>=n) return;
  int d = dst[i];
  int p = off[d] + atomicAdd(&cur[d],1);
  csr[p] = i;
}

// ---------------- fused gather + MFMA GEMM ----------------
// MODE 0: first GEMM,  KT=2:  A=[atom[src]|bond],            out msg = relu(A@Wi)
// MODE 1: iteration,   KT=12: A=[feats | segsum_lg(msg_in)], out msg = relu(A@[Wi;Wh])
// MODE 2: final,       KT=11: A=[atom | segsum_at(msg_in)],  pooled relu(A@Wo + bo)
// A-frag: chunk (rowgroup, kt): lane l, elem j -> A[rg*16+(l&15)][kt*32+(l>>4)*8+j]
// block = 128 rows x 320 cols, 4 waves (wave tile 64x160)
template<int MODE>
__launch_bounds__(256,2)
__global__ void gemm_fused(const float* __restrict__ atomf,
                           const float* __restrict__ bondf,
                           const int*   __restrict__ esrc,
                           const u16*   __restrict__ msgin,
                           const u16*   __restrict__ Bfrag,
                           u16*         __restrict__ msgout,
                           const int*   __restrict__ off,
                           const int*   __restrict__ csr,
                           const float* __restrict__ bo,
                           const int*   __restrict__ gids,
                           float*       __restrict__ pacc)
{
  constexpr int KT    = (MODE==0) ? 2 : (MODE==1 ? 12 : 11);
  constexpr int SHIFT = (MODE==2) ? 48 : 64;   // A col k -> msg col k-SHIFT
  constexpr int NROWS = (MODE==2) ? NA : NE;
  __shared__ u16 lds[2][28*512];               // 8 A-chunks + 20 B-chunks, 1KB each; 56KB total
  const int t = threadIdx.x, w = t>>6, lane = t&63;
  const int wr = w>>1, wc = w&1;
  const int m0g = blockIdx.x*8;
  const int r16 = lane&15, gc = lane>>4;

  // hoisted per-staged-row state (wave w stages rowgroups m0g+2w, m0g+2w+1)
  int rowv[2], srcv[2], S0[2], S1[2];
  #pragma unroll
  for (int i=0;i<2;++i){
    const int row = (m0g + w*2 + i)*16 + r16;
    rowv[i] = row;
    if constexpr (MODE<=1) srcv[i] = (row < NE) ? esrc[row] : 0;
    else                   srcv[i] = 0;
    if constexpr (MODE>=1){
      if (row < NROWS){ S0[i]=off[row]; S1[i]=off[row+1]; } else { S0[i]=0; S1[i]=0; }
    } else { S0[i]=0; S1[i]=0; }
  }

  f4v acc[4][10];
  const f4v fz = {0.f,0.f,0.f,0.f};
  #pragma unroll
  for (int i=0;i<4;++i)
    #pragma unroll
    for (int n=0;n<10;++n) acc[i][n] = fz;

  auto stageA = [&](int buf, int kt){
    #pragma unroll
    for (int i=0;i<2;++i){
      const int row = rowv[i];
      const int k0  = kt*32 + gc*8;
      float v[8];
      bool isfeat;
      if constexpr (MODE==2) isfeat = (kt==0) || (kt==1 && gc<2);
      else                   isfeat = (kt<2);
      if (isfeat){
        if constexpr (MODE<=1){
          const int  src = srcv[i];
          const bool ok  = row < NE;
          #pragma unroll
          for (int j=0;j<8;++j){
            const int k = k0+j;
            float x = 0.f;
            if (ok){
              if (k < AF) x = atomf[(size_t)src*AF + k];
              else if (k < AF+BFD) x = bondf[(size_t)row*BFD + (k-AF)];
            }
            v[j] = x;
          }
        } else {
          const bool ok = row < NA;
          #pragma unroll
          for (int j=0;j<8;++j){
            const int k = k0+j;
            v[j] = (ok && k < AF) ? atomf[(size_t)row*AF + k] : 0.f;
          }
        }
      } else {
        const int cb = k0 - SHIFT;               // multiple of 8 -> 16B aligned reads
        float a8[8] = {0,0,0,0,0,0,0,0};
        for (int it=S0[i]; it<S1[i]; ++it){
          const int sidx = csr[it];
          const u16x8 mv = *(const u16x8*)(msgin + (size_t)sidx*MS + cb);
          #pragma unroll
          for (int j=0;j<8;++j) a8[j] += bf2f(mv[j]);
        }
        #pragma unroll
        for (int j=0;j<8;++j) v[j] = a8[j];
      }
      u16x8 o;
      #pragma unroll
      for (int j=0;j<8;++j) o[j] = f2bf(v[j]);
      *(u16x8*)(&lds[buf][(w*2+i)*512 + lane*8]) = o;   // ds_write_b128, linear
    }
    #pragma unroll
    for (int i=0;i<5;++i){
      const int nt = w*5+i;
      GLOAD_LDS16(Bfrag + ((size_t)kt*NT + nt)*512 + lane*8, &lds[buf][(8+nt)*512]);
    }
  };

  int buf = 0;
  stageA(0, 0);
  __syncthreads();
  for (int kt=0; kt<KT; ++kt){
    if (kt+1 < KT) stageA(buf^1, kt+1);
    s8v a[4];
    #pragma unroll
    for (int i=0;i<4;++i) a[i] = *(const s8v*)&lds[buf][(wr*4+i)*512 + lane*8];
    #pragma unroll
    for (int h2=0; h2<2; ++h2){
      s8v b[5];
      #pragma unroll
      for (int n=0;n<5;++n) b[n] = *(const s8v*)&lds[buf][(8 + wc*10 + h2*5 + n)*512 + lane*8];
      #pragma unroll
      for (int n=0;n<5;++n)
        #pragma unroll
        for (int i=0;i<4;++i)
          acc[i][h2*5+n] = __builtin_amdgcn_mfma_f32_16x16x32_bf16(a[i], b[n], acc[i][h2*5+n], 0,0,0);
    }
    __syncthreads();
    buf ^= 1;
  }

  // epilogue. C/D frag: col = lane&15, row = (lane>>4)*4 + r
  const int colL = r16;
  const int row0 = m0g*16 + wr*64 + (gc<<2);
  if constexpr (MODE<=1){
    #pragma unroll
    for (int n=0;n<10;++n){
      const int col = wc*160 + n*16 + colL;
      if (col >= HID) continue;
      #pragma unroll
      for (int i=0;i<4;++i)
        #pragma unroll
        for (int r=0;r<4;++r){
          const int row = row0 + i*16 + r;
          msgout[(size_t)row*MS + col] = f2bf(fmaxf(acc[i][n][r], 0.f));
        }
    }
  } else {
    // fused per-graph pooling: block's 128 rows span <=3 graphs (monotone gids)
    float* pl = (float*)&lds[0][0];              // 3*320 floats, LDS reuse after k-loop barrier
    for (int idx=t; idx<960; idx+=256) pl[idx] = 0.f;
    __syncthreads();
    const int gb = gids[m0g*16];
    #pragma unroll
    for (int n=0;n<10;++n){
      const int col = wc*160 + n*16 + colL;
      if (col >= HID) continue;
      const float bv = bo[col];
      #pragma unroll
      for (int i=0;i<4;++i)
        #pragma unroll
        for (int r=0;r<4;++r){
          const int row = row0 + i*16 + r;
          if (row >= NA) continue;
          const float h = fmaxf(acc[i][n][r] + bv, 0.f);
          const int gl = gids[row] - gb;
          atomicAdd(&pl[gl*320 + col], h);
        }
    }
    __syncthreads();
    for (int idx=t; idx<960; idx+=256){
      const int g = idx/320, c = idx - g*320;
      if (c < HID){
        const int gg = gb + g;
        if (gg < NG){
          const float vv = pl[idx];
          if (vv != 0.f) atomicAdd(&pacc[(size_t)gg*HID + c], vv);
        }
      }
    }
  }
}

// ---------------- scale: out = pacc / count over contiguous graph ranges ----------------
__device__ inline int lbound(const int* a, int n, int v){
  int lo=0, hi=n;
  while (lo<hi){ int m=(lo+hi)>>1; if (a[m]<v) lo=m+1; else hi=m; }
  return lo;
}
__global__ void scale_k(const float* __restrict__ pacc, const int* __restrict__ gids,
                        float* __restrict__ out){
  const int g = blockIdx.x, t = threadIdx.x;
  __shared__ int se[2];
  if (t < 2) se[t] = lbound(gids, NA, g+t);
  __syncthreads();
  const float inv = 1.0f / (float)((se[1]-se[0]) > 1 ? (se[1]-se[0]) : 1);
  for (int c=t; c<HID; c+=256)
    out[(size_t)g*HID + c] = pacc[(size_t)g*HID + c] * inv;
}

// ---------------- launcher ----------------
extern "C" void kernel_launch(void* const* d_in, const int* in_sizes, int n_in,
                              void* d_out, int out_size, void* d_ws, size_t ws_size,
                              hipStream_t stream)
{
  const float* atomf = (const float*)d_in[0];
  const float* bondf = (const float*)d_in[1];
  const float* W_i   = (const float*)d_in[2];
  const float* W_h   = (const float*)d_in[3];
  const float* W_o   = (const float*)d_in[4];
  const float* b_o   = (const float*)d_in[5];
  const int*   esrc  = (const int*)d_in[6];
  const int*   edst  = (const int*)d_in[7];
  const int*   lsrc  = (const int*)d_in[8];
  const int*   ldst  = (const int*)d_in[9];
  const int*   gids  = (const int*)d_in[10];

  char* ws = (char*)d_ws;
  size_t wsoff = 0;
  auto walloc = [&](size_t bytes)->void*{
    void* p = ws + wsoff;
    wsoff += (bytes + 1023) & ~(size_t)1023;
    return p;
  };
  u16*  m0    = (u16*) walloc((size_t)E_PAD*MS*2);   // 121.6 MB
  u16*  m1    = (u16*) walloc((size_t)E_PAD*MS*2);   // 121.6 MB
  u16*  whif  = (u16*) walloc((size_t)12*NT*512*2);
  u16*  wof   = (u16*) walloc((size_t)11*NT*512*2);
  int* off_lg = (int*) walloc((size_t)(NE+1)*4);
  int* csr_lg = (int*) walloc((size_t)NLG*4);
  int* cnt_lg = (int*) walloc((size_t)NE*4);
  int* cur_lg = (int*) walloc((size_t)NE*4);
  int* off_at = (int*) walloc((size_t)(NA+1)*4);
  int* csr_at = (int*) walloc((size_t)NE*4);
  int* cnt_at = (int*) walloc((size_t)NA*4);
  int* cur_at = (int*) walloc((size_t)NA*4);
  int* part1  = (int*) walloc(256*4);
  int* pref1  = (int*) walloc(256*4);
  int* part2  = (int*) walloc(256*4);
  int* pref2  = (int*) walloc(256*4);
  float* pacc = (float*)walloc((size_t)NG*HID*4);    // 1.23 MB
  // total ~251.0 MB

  if (wsoff > ws_size) return;   // diagnostic: clean zero-output instead of OOB fault

  hipMemsetAsync(cnt_lg, 0, (size_t)NE*4, stream);
  hipMemsetAsync(cur_lg, 0, (size_t)NE*4, stream);
  hipMemsetAsync(cnt_at, 0, (size_t)NA*4, stream);
  hipMemsetAsync(cur_at, 0, (size_t)NA*4, stream);
  hipMemsetAsync(pacc,   0, (size_t)NG*HID*4, stream);

  prep_whi<<<480,256,0,stream>>>(W_i, W_h, whif);
  prep_wo <<<440,256,0,stream>>>(W_o, wof);

  hist_k<<<(NLG+255)/256,256,0,stream>>>(ldst, cnt_lg, NLG);
  hist_k<<<(NE+255)/256,256,0,stream>>>(edst, cnt_at, NE);
  scan1<<<196,256,0,stream>>>(cnt_lg, off_lg, part1, NE);
  scan2<<<1,256,0,stream>>>(part1, pref1, 196);
  scan3<<<196,256,0,stream>>>(off_lg, pref1, part1, NE, 196);
  scan1<<<98,256,0,stream>>>(cnt_at, off_at, part2, NA);
  scan2<<<1,256,0,stream>>>(part2, pref2, 98);
  scan3<<<98,256,0,stream>>>(off_at, pref2, part2, NA, 98);
  scatter_val<<<(NLG+255)/256,256,0,stream>>>(ldst, lsrc, off_lg, cur_lg, csr_lg, NLG);
  scatter_idx<<<(NE+255)/256,256,0,stream>>>(edst, off_at, cur_at, csr_at, NE);

  // msg0 = relu(feats @ W_i)
  gemm_fused<0><<<E_PAD/128,256,0,stream>>>(atomf, bondf, esrc, m0, whif, m0,
                                            off_lg, csr_lg, nullptr, nullptr, nullptr);

  // iterations: msg_out = relu([feats | segsum_lg(msg_in)] @ [W_i ; W_h])
  for (int d=0; d<DEPTH-1; ++d){
    const u16* min_ = (d & 1) ? m1 : m0;
    u16*       mout = (d & 1) ? m0 : m1;
    gemm_fused<1><<<E_PAD/128,256,0,stream>>>(atomf, bondf, esrc, min_, whif, mout,
                                              off_lg, csr_lg, nullptr, nullptr, nullptr);
  }

  // final: pooled relu([atom | segsum_at(msg)] @ W_o + b_o)   (5 iters -> result in m1)
  gemm_fused<2><<<A_PAD/128,256,0,stream>>>(atomf, bondf, nullptr, m1, wof, nullptr,
                                            off_at, csr_at, b_o, gids, pacc);

  scale_k<<<NG,256,0,stream>>>(pacc, gids, (float*)d_out);
}

// Round 4
// 1294.597 us; speedup vs baseline: 1.6320x; 1.6320x over previous
//
#include <hip/hip_runtime.h>
#include <stdint.h>

#define NA 100000
#define NE 200000
#define NLG 400000
#define NG 1024
#define AF 39
#define BFD 11
#define HID 300
#define DEPTH 6

#define E_PAD 200064    // edges padded to multiple of 128
#define A_PAD 100096    // atoms padded to multiple of 128
#define EG 12504        // E_PAD/16 rowgroups
#define AGR 6250        // NA/16 (exact)
#define AG2 6256        // A_PAD/16 rowgroups
#define MS 304          // msg row stride in u16 (608 B -> 16B aligned)
#define NT 20           // N tiles (320 cols, 300 real)

typedef unsigned short u16;
typedef __attribute__((ext_vector_type(8))) short s8v;            // 8 bf16 bits (A/B frag)
typedef __attribute__((ext_vector_type(8))) unsigned short u16x8;
typedef __attribute__((ext_vector_type(4))) float f4v;            // C/D frag

__device__ inline u16 f2bf(float x){
  unsigned u = __float_as_uint(x);
  u += 0x7FFFu + ((u>>16)&1u);   // RNE
  return (u16)(u>>16);
}
__device__ inline float bf2f(u16 b){ return __uint_as_float(((unsigned)b)<<16); }

#define GLOAD_LDS16(gp, lp) __builtin_amdgcn_global_load_lds( \
    (const __attribute__((address_space(1))) void*)(gp), \
    (__attribute__((address_space(3))) void*)(lp), 16, 0, 0)

// ---------------- weight packing to fragment order ----------------
// B-frag element (kt, nt, lane, j) <-> B[k = kt*32 + (lane>>4)*8 + j][n = nt*16 + (lane&15)]
// stacked [W_i ; zero-pad ; W_h]: k<50 -> W_i[k]; 64<=k<364 -> W_h[k-64]; else 0
__global__ void prep_whi(const float* __restrict__ Wi, const float* __restrict__ Wh,
                         u16* __restrict__ Wf){
  int idx = blockIdx.x*256 + threadIdx.x;
  const int total = 12*NT*512;
  if (idx >= total) return;
  int j    = idx & 7;
  int lane = (idx>>3) & 63;
  int tile = idx >> 9;
  int nt = tile % NT, kt = tile / NT;
  int k = kt*32 + ((lane>>4)<<3) + j;
  int n = nt*16 + (lane&15);
  float v = 0.f;
  if (n < HID){
    if (k < AF+BFD) v = Wi[(size_t)k*HID + n];
    else if (k >= 64 && k < 64+HID) v = Wh[(size_t)(k-64)*HID + n];
  }
  Wf[idx] = f2bf(v);
}

// W_o row remap: k<39 -> k ; 48<=k<348 -> k-9 ; else zero   (W_o has 339 rows)
__global__ void prep_wo(const float* __restrict__ W, u16* __restrict__ Wf){
  int idx = blockIdx.x*256 + threadIdx.x;
  const int total = 11*NT*512;
  if (idx >= total) return;
  int j    = idx & 7;
  int lane = (idx>>3) & 63;
  int tile = idx >> 9;
  int nt = tile % NT, kt = tile / NT;
  int k = kt*32 + ((lane>>4)<<3) + j;
  int n = nt*16 + (lane&15);
  int ks = (k < AF) ? k : ((k >= 48 && k < 348) ? (k-9) : -1);
  float v = 0.f;
  if (ks >= 0 && n < HID) v = W[(size_t)ks*HID + n];
  Wf[idx] = f2bf(v);
}

// ---------------- CSR build ----------------
__global__ void hist_k(const int* __restrict__ dst, int* __restrict__ cnt, int n){
  int i = blockIdx.x*256 + threadIdx.x;
  if (i < n) atomicAdd(&cnt[dst[i]], 1);
}
__global__ void scan1(const int* __restrict__ cnt, int* __restrict__ off,
                      int* __restrict__ part, int n){
  __shared__ int s[256];
  const int t = threadIdx.x, b = blockIdx.x;
  const int i0 = b*1024 + t*4;
  int v0 = (i0+0<n)?cnt[i0+0]:0, v1=(i0+1<n)?cnt[i0+1]:0, v2=(i0+2<n)?cnt[i0+2]:0, v3=(i0+3<n)?cnt[i0+3]:0;
  int sum = v0+v1+v2+v3;
  s[t]=sum; __syncthreads();
  for (int o=1;o<256;o<<=1){ int x=(t>=o)?s[t-o]:0; __syncthreads(); s[t]+=x; __syncthreads(); }
  int excl = s[t]-sum;
  if (i0+0<n) off[i0+0]=excl;
  if (i0+1<n) off[i0+1]=excl+v0;
  if (i0+2<n) off[i0+2]=excl+v0+v1;
  if (i0+3<n) off[i0+3]=excl+v0+v1+v2;
  if (t==255) part[b]=s[255];
}
__global__ void scan2(const int* __restrict__ part, int* __restrict__ pref, int nblk){
  __shared__ int s[256];
  const int t = threadIdx.x;
  int v = (t<nblk)?part[t]:0;
  s[t]=v; __syncthreads();
  for (int o=1;o<256;o<<=1){ int x=(t>=o)?s[t-o]:0; __syncthreads(); s[t]+=x; __syncthreads(); }
  pref[t] = s[t]-v;
}
__global__ void scan3(int* __restrict__ off, const int* __restrict__ pref,
                      const int* __restrict__ part, int n, int nblk){
  const int t = threadIdx.x, b = blockIdx.x;
  const int i0 = b*1024 + t*4;
  const int p = pref[b];
  #pragma unroll
  for (int k=0;k<4;++k) if (i0+k<n) off[i0+k]+=p;
  if (b==0 && t==0) off[n] = pref[nblk-1] + part[nblk-1];
}
__global__ void scatter_val(const int* __restrict__ dst, const int* __restrict__ src,
                            const int* __restrict__ off, int* __restrict__ cur,
                            int* __restrict__ csr, int n){
  int i = blockIdx.x*256 + threadIdx.x; if (i>=n) return;
  int d = dst[i];
  int p = off[d] + atomicAdd(&cur[d],1);
  csr[p] = src[i];
}
__global__ void scatter_idx(const int* __restrict__ dst, const int* __restrict__ off,
                            int* __restrict__ cur, int* __restrict__ csr, int n){
  int i = blockIdx.x*256 + threadIdx.x; if (i>=n) return;
  int d = dst[i];
  int p = off[d] + atomicAdd(&cur[d],1);
  csr[p] = i;
}

// ---------------- latency-optimized gathers (segment_sum -> fragment order) ----------------
// lane: row r16 = lane&15, chunk-quarter gc = lane>>4 (8 cols each).
// Per neighbor: 10 independent 16B loads in flight; acc[10][8] f32 in regs.
__launch_bounds__(256,3)
__global__ void gather_lg_k(const u16* __restrict__ msg, u16* __restrict__ accf,
                            const int* __restrict__ off, const int* __restrict__ csr){
  const int w = threadIdx.x>>6, lane = threadIdx.x&63;
  const int g16 = blockIdx.x*4 + w;
  if (g16 >= EG) return;
  const int e = g16*16 + (lane&15);
  const int gc = lane>>4;
  int s=0, epos=0;
  if (e < NE){ s = off[e]; epos = off[e+1]; }
  float acc[10][8];
  #pragma unroll
  for (int c=0;c<10;++c)
    #pragma unroll
    for (int j=0;j<8;++j) acc[c][j] = 0.f;
  const bool c9live = (gc < 2);   // chunk 9 cols 288..303 only (cols>=304 don't exist)
  for (int it=s; it<epos; ++it){
    const int src = csr[it];
    const u16* base = msg + (size_t)src*MS + gc*8;
    u16x8 v[10];
    #pragma unroll
    for (int c=0;c<9;++c) v[c] = *(const u16x8*)(base + c*32);
    if (c9live) v[9] = *(const u16x8*)(base + 288);
    else { u16x8 z = {0,0,0,0,0,0,0,0}; v[9] = z; }
    #pragma unroll
    for (int c=0;c<10;++c)
      #pragma unroll
      for (int j=0;j<8;++j) acc[c][j] += bf2f(v[c][j]);
  }
  #pragma unroll
  for (int c=0;c<10;++c){
    u16x8 o;
    #pragma unroll
    for (int j=0;j<8;++j) o[j] = f2bf(acc[c][j]);
    *(u16x8*)(accf + ((size_t)g16*10 + c)*512 + lane*8) = o;
  }
}

// atom-side: atf chunks kt=1..10. kt==1/gc<2 slots hold atom feats k=32..47; rest = segsum cols k-48.
__launch_bounds__(256,3)
__global__ void gather_at_k(const u16* __restrict__ msg, const float* __restrict__ atomf,
                            u16* __restrict__ atf,
                            const int* __restrict__ off, const int* __restrict__ csr){
  const int w = threadIdx.x>>6, lane = threadIdx.x&63;
  const int g16 = blockIdx.x*4 + w;
  if (g16 >= AGR) return;
  const int a = g16*16 + (lane&15);
  const int gc = lane>>4;
  const int s = off[a], epos = off[a+1];
  float acc[10][8];
  #pragma unroll
  for (int c=0;c<10;++c)
    #pragma unroll
    for (int j=0;j<8;++j) acc[c][j] = 0.f;
  const bool k1live = (gc >= 2);  // kt=1: gc>=2 -> msg cols 0..15; gc<2 -> atom feats
  for (int it=s; it<epos; ++it){
    const int src = csr[it];
    const u16* base = msg + (size_t)src*MS + gc*8 - 48;  // col = kt*32 + gc*8 - 48
    u16x8 v[10];
    if (k1live) v[0] = *(const u16x8*)(base + 32);
    else { u16x8 z = {0,0,0,0,0,0,0,0}; v[0] = z; }
    #pragma unroll
    for (int kt=2; kt<=10; ++kt) v[kt-1] = *(const u16x8*)(base + kt*32);
    #pragma unroll
    for (int c=0;c<10;++c)
      #pragma unroll
      for (int j=0;j<8;++j) acc[c][j] += bf2f(v[c][j]);
  }
  #pragma unroll
  for (int kt=1; kt<=10; ++kt){
    u16x8 o;
    if (kt==1 && !k1live){
      #pragma unroll
      for (int j=0;j<8;++j){
        const int k = 32 + gc*8 + j;
        o[j] = f2bf((k < AF) ? atomf[(size_t)a*AF + k] : 0.f);
      }
    } else {
      #pragma unroll
      for (int j=0;j<8;++j) o[j] = f2bf(acc[kt-1][j]);
    }
    *(u16x8*)(atf + ((size_t)g16*11 + kt)*512 + lane*8) = o;
  }
}

// atf chunk kt=0: atom feats k=0..31 (all < AF=39 real)
__global__ void prep_atom(const float* __restrict__ atomf, u16* __restrict__ atf){
  const int w = threadIdx.x>>6, lane = threadIdx.x&63;
  const int g16 = blockIdx.x*4 + w;
  if (g16 >= AGR) return;
  const int a = g16*16 + (lane&15);
  const int gc = lane>>4;
  u16x8 o;
  #pragma unroll
  for (int j=0;j<8;++j) o[j] = f2bf(atomf[(size_t)a*AF + gc*8 + j]);
  *(u16x8*)(atf + ((size_t)g16*11 + 0)*512 + lane*8) = o;
}

// ---------------- MFMA GEMM: 128x320 block, 4 waves (wave tile 64x160) ----------------
// MODE 0: KT=2,  A = [atom[src]|bond] computed in-kernel;        out msg = relu(A@Wi)
// MODE 1: KT=12, kt<2 computed feats, kt>=2 gload from accf;     out msg = relu(A@[Wi;Wh])
// MODE 2: KT=11, all kt gload from atf;                          pooled relu(A@Wo+bo) -> gout
template<int MODE>
__launch_bounds__(256,2)
__global__ void gemm_fused(const float* __restrict__ atomf,
                           const float* __restrict__ bondf,
                           const int*   __restrict__ esrc,
                           const u16*   __restrict__ Afrag,
                           const u16*   __restrict__ Bfrag,
                           u16*         __restrict__ msgout,
                           const float* __restrict__ bo,
                           const int*   __restrict__ gids,
                           float*       __restrict__ gout)
{
  constexpr int KT = (MODE==0) ? 2 : (MODE==1 ? 12 : 11);
  __shared__ u16 lds[2][28*512];               // 8 A-chunks + 20 B-chunks, 1KB each; 56KB
  const int t = threadIdx.x, w = t>>6, lane = t&63;
  const int wr = w>>1, wc = w&1;
  const int m0g = blockIdx.x*8;
  const int r16 = lane&15, gc = lane>>4;

  int rowv[2], srcv[2];
  #pragma unroll
  for (int i=0;i<2;++i){
    const int row = (m0g + w*2 + i)*16 + r16;
    rowv[i] = row;
    if constexpr (MODE<=1) srcv[i] = (row < NE) ? esrc[row] : 0;
    else                   srcv[i] = 0;
  }

  f4v acc[4][10];
  const f4v fz = {0.f,0.f,0.f,0.f};
  #pragma unroll
  for (int i=0;i<4;++i)
    #pragma unroll
    for (int n=0;n<10;++n) acc[i][n] = fz;

  auto stageA = [&](int buf, int kt){
    if constexpr (MODE==2){
      #pragma unroll
      for (int i=0;i<2;++i){
        const int rg = m0g + w*2 + i;
        GLOAD_LDS16(Afrag + ((size_t)rg*11 + kt)*512 + lane*8, &lds[buf][(w*2+i)*512]);
      }
    } else {
      if (MODE==1 && kt >= 2){
        #pragma unroll
        for (int i=0;i<2;++i){
          const int rg = m0g + w*2 + i;
          GLOAD_LDS16(Afrag + ((size_t)rg*10 + (kt-2))*512 + lane*8, &lds[buf][(w*2+i)*512]);
        }
      } else {
        #pragma unroll
        for (int i=0;i<2;++i){
          const int row = rowv[i];
          const int src = srcv[i];
          const bool ok = row < NE;
          const int k0  = kt*32 + gc*8;
          u16x8 o;
          #pragma unroll
          for (int j=0;j<8;++j){
            const int k = k0+j;
            float x = 0.f;
            if (ok){
              if (k < AF) x = atomf[(size_t)src*AF + k];
              else if (k < AF+BFD) x = bondf[(size_t)row*BFD + (k-AF)];
            }
            o[j] = f2bf(x);
          }
          *(u16x8*)(&lds[buf][(w*2+i)*512 + lane*8]) = o;
        }
      }
    }
    #pragma unroll
    for (int i=0;i<5;++i){
      const int nt = w*5+i;
      GLOAD_LDS16(Bfrag + ((size_t)kt*NT + nt)*512 + lane*8, &lds[buf][(8+nt)*512]);
    }
  };

  int buf = 0;
  stageA(0, 0);
  __syncthreads();
  for (int kt=0; kt<KT; ++kt){
    if (kt+1 < KT) stageA(buf^1, kt+1);
    s8v a[4];
    #pragma unroll
    for (int i=0;i<4;++i) a[i] = *(const s8v*)&lds[buf][(wr*4+i)*512 + lane*8];
    #pragma unroll
    for (int h2=0; h2<2; ++h2){
      s8v b[5];
      #pragma unroll
      for (int n=0;n<5;++n) b[n] = *(const s8v*)&lds[buf][(8 + wc*10 + h2*5 + n)*512 + lane*8];
      #pragma unroll
      for (int n=0;n<5;++n)
        #pragma unroll
        for (int i=0;i<4;++i)
          acc[i][h2*5+n] = __builtin_amdgcn_mfma_f32_16x16x32_bf16(a[i], b[n], acc[i][h2*5+n], 0,0,0);
    }
    __syncthreads();
    buf ^= 1;
  }

  // epilogue. C/D frag: col = lane&15, row = (lane>>4)*4 + r
  const int colL = r16;
  const int row0 = m0g*16 + wr*64 + (gc<<2);
  if constexpr (MODE<=1){
    #pragma unroll
    for (int n=0;n<10;++n){
      const int col = wc*160 + n*16 + colL;
      if (col >= MS) continue;
      #pragma unroll
      for (int i=0;i<4;++i)
        #pragma unroll
        for (int r=0;r<4;++r){
          const int row = row0 + i*16 + r;
          const float v = (col < HID) ? fmaxf(acc[i][n][r], 0.f) : 0.f;  // zero-pad 300..303
          msgout[(size_t)row*MS + col] = f2bf(v);
        }
    }
  } else {
    // fused per-graph pooling: block's 128 rows span <=3 graphs (monotone gids)
    float* pl = (float*)&lds[0][0];
    for (int idx=t; idx<960; idx+=256) pl[idx] = 0.f;
    __syncthreads();
    const int gb = gids[m0g*16 < NA ? m0g*16 : (NA-1)];
    #pragma unroll
    for (int n=0;n<10;++n){
      const int col = wc*160 + n*16 + colL;
      if (col >= HID) continue;
      const float bv = bo[col];
      #pragma unroll
      for (int i=0;i<4;++i)
        #pragma unroll
        for (int r=0;r<4;++r){
          const int row = row0 + i*16 + r;
          if (row >= NA) continue;
          const float h = fmaxf(acc[i][n][r] + bv, 0.f);
          const int gl = gids[row] - gb;
          atomicAdd(&pl[gl*320 + col], h);
        }
    }
    __syncthreads();
    for (int idx=t; idx<960; idx+=256){
      const int g = idx/320, c = idx - g*320;
      if (c < HID){
        const int gg = gb + g;
        if (gg < NG){
          const float vv = pl[idx];
          if (vv != 0.f) atomicAdd(&gout[(size_t)gg*HID + c], vv);
        }
      }
    }
  }
}

// ---------------- scale: out = out / count over contiguous graph ranges (in place) ----------------
__device__ inline int lbound(const int* a, int n, int v){
  int lo=0, hi=n;
  while (lo<hi){ int m=(lo+hi)>>1; if (a[m]<v) lo=m+1; else hi=m; }
  return lo;
}
__global__ void scale_k(float* __restrict__ out, const int* __restrict__ gids){
  const int g = blockIdx.x, t = threadIdx.x;
  __shared__ int se[2];
  if (t < 2) se[t] = lbound(gids, NA, g+t);
  __syncthreads();
  const float inv = 1.0f / (float)((se[1]-se[0]) > 1 ? (se[1]-se[0]) : 1);
  for (int c=t; c<HID; c+=256)
    out[(size_t)g*HID + c] *= inv;
}

// ---------------- launcher ----------------
extern "C" void kernel_launch(void* const* d_in, const int* in_sizes, int n_in,
                              void* d_out, int out_size, void* d_ws, size_t ws_size,
                              hipStream_t stream)
{
  const float* atomf = (const float*)d_in[0];
  const float* bondf = (const float*)d_in[1];
  const float* W_i   = (const float*)d_in[2];
  const float* W_h   = (const float*)d_in[3];
  const float* W_o   = (const float*)d_in[4];
  const float* b_o   = (const float*)d_in[5];
  const int*   esrc  = (const int*)d_in[6];
  const int*   edst  = (const int*)d_in[7];
  const int*   lsrc  = (const int*)d_in[8];
  const int*   ldst  = (const int*)d_in[9];
  const int*   gids  = (const int*)d_in[10];

  char* ws = (char*)d_ws;
  size_t wsoff = 0;
  auto walloc = [&](size_t bytes)->void*{
    void* p = ws + wsoff;
    wsoff += (bytes + 1023) & ~(size_t)1023;
    return p;
  };
  u16*  m0    = (u16*) walloc((size_t)E_PAD*MS*2);       // 121.64 MB : msg (in-place per iter)
  u16*  m1    = (u16*) walloc((size_t)EG*10*1024);       // 128.04 MB : accf; later atf (6256*11KB)
  u16*  atf   = m1;
  u16*  whif  = (u16*) walloc((size_t)12*NT*512*2);
  u16*  wof   = (u16*) walloc((size_t)11*NT*512*2);
  int* off_lg = (int*) walloc((size_t)(NE+1)*4);
  int* csr_lg = (int*) walloc((size_t)NLG*4);
  int* buf_lg = (int*) walloc((size_t)NE*4);             // cnt then cur
  int* off_at = (int*) walloc((size_t)(NA+1)*4);
  int* csr_at = (int*) walloc((size_t)NE*4);
  int* buf_at = (int*) walloc((size_t)NA*4);             // cnt then cur
  int* part1  = (int*) walloc(256*4);
  int* pref1  = (int*) walloc(256*4);
  int* part2  = (int*) walloc(256*4);
  int* pref2  = (int*) walloc(256*4);
  // total ~255.0 MB

  if (wsoff > ws_size) return;   // diagnostic: clean zero-output instead of OOB fault

  float* gout = (float*)d_out;
  hipMemsetAsync(gout,   0, (size_t)out_size*4, stream);
  hipMemsetAsync(buf_lg, 0, (size_t)NE*4, stream);
  hipMemsetAsync(buf_at, 0, (size_t)NA*4, stream);

  prep_whi<<<480,256,0,stream>>>(W_i, W_h, whif);
  prep_wo <<<440,256,0,stream>>>(W_o, wof);

  hist_k<<<(NLG+255)/256,256,0,stream>>>(ldst, buf_lg, NLG);
  hist_k<<<(NE+255)/256,256,0,stream>>>(edst, buf_at, NE);
  scan1<<<196,256,0,stream>>>(buf_lg, off_lg, part1, NE);
  scan2<<<1,256,0,stream>>>(part1, pref1, 196);
  scan3<<<196,256,0,stream>>>(off_lg, pref1, part1, NE, 196);
  scan1<<<98,256,0,stream>>>(buf_at, off_at, part2, NA);
  scan2<<<1,256,0,stream>>>(part2, pref2, 98);
  scan3<<<98,256,0,stream>>>(off_at, pref2, part2, NA, 98);
  hipMemsetAsync(buf_lg, 0, (size_t)NE*4, stream);       // reuse as cur
  hipMemsetAsync(buf_at, 0, (size_t)NA*4, stream);
  scatter_val<<<(NLG+255)/256,256,0,stream>>>(ldst, lsrc, off_lg, buf_lg, csr_lg, NLG);
  scatter_idx<<<(NE+255)/256,256,0,stream>>>(edst, off_at, buf_at, csr_at, NE);

  // msg = relu(feats @ W_i)
  gemm_fused<0><<<E_PAD/128,256,0,stream>>>(atomf, bondf, esrc, nullptr, whif, m0,
                                            nullptr, nullptr, nullptr);

  // iterations: accf = segsum_lg(msg) [frag order]; msg = relu([feats|accf] @ [Wi;Wh]) in place
  for (int d=0; d<DEPTH-1; ++d){
    gather_lg_k<<<EG/4,256,0,stream>>>(m0, m1, off_lg, csr_lg);
    gemm_fused<1><<<E_PAD/128,256,0,stream>>>(atomf, bondf, esrc, m1, whif, m0,
                                              nullptr, nullptr, nullptr);
  }

  // final: atf = [atom | segsum_at(msg)] frag order; pooled relu(atf @ Wo + bo) -> d_out
  prep_atom  <<<(AGR+3)/4,256,0,stream>>>(atomf, atf);
  gather_at_k<<<(AGR+3)/4,256,0,stream>>>(m0, atomf, atf, off_at, csr_at);
  gemm_fused<2><<<A_PAD/128,256,0,stream>>>(atomf, bondf, nullptr, atf, wof, nullptr,
                                            b_o, gids, gout);

  scale_k<<<NG,256,0,stream>>>(gout, gids);
}